// Round 12
// baseline (599.054 us; speedup 1.0000x reference)
//
#include <hip/hip_runtime.h>
#include <hip/hip_bf16.h>

// Problem: N=4,C=64,F=100,T=200,H=16 ; B=N*F=400, BT=80000
// r12: fixes r11's divergent-__syncthreads race in k_attn (absmax 2.78 --
// s_barrier inside if/else executes at wave granularity in unspecified
// branch order -> half1 could read ps before half0 wrote it). Balanced
// row-pairing kept, but restructured: phase 1 = all threads compute (half0:
// row p full -> att, row 199-p tail -> ps LDS; half1: row 199-p head -> regs);
// ONE uniform __syncthreads(); phase 2 = half1 combines ps + regs, writes.
// k_lstm = r7 exact (best measured 197us: fused MFMA input-GEMM + recurrence,
// LDS weights, DPP h-broadcast; r8 scalar / r9 asm-pk / r10 dual-stream all
// neutral-or-worse -- locally converged at ~345 instr/step, 66% VALUBusy).
// Pipeline per chunk: ln1 (fp32->bf16 xr/xi) -> k_lstm -> attention (mult.
// causal mask BEFORE softmax, suffix-V, balanced pairing) -> combine+LN2+
// complex linear+LN3+PReLU+residual.
// ws: header 204800 B (bihh fp32 @0, Wih-bf16 @8192), then per chunk:
//   xr bf16 [NB][200][64], xi same, h f32 [24][NB][200][16],
//   att f32 [8][NB][200][16].  Total = 204800 + NB*460800.

typedef __attribute__((ext_vector_type(8))) short bf16x8;
typedef __attribute__((ext_vector_type(4))) float f32x4;
typedef __attribute__((ext_vector_type(2))) float f32x2;

static __device__ __forceinline__ float bf2f(unsigned short u) {
  return __uint_as_float(((unsigned)u) << 16);
}
static __device__ __forceinline__ unsigned short f2bfu(float x) {
  __hip_bfloat16 h = __float2bfloat16(x);
  return *(unsigned short*)&h;
}
static __device__ __forceinline__ float sigf(float x) {
  return __fdividef(1.f, 1.f + __expf(-x));
}
static __device__ __forceinline__ float tanh_(float x) {
  return 1.f - __fdividef(2.f, __expf(2.f * x) + 1.f);  // safe at +-inf
}
static __device__ __forceinline__ f32x2 hh2(float v) {
  f32x2 r; r.x = v; r.y = v; return r;
}

// Broadcast lane (row-base + I) of h to all 16 lanes of its row.
// ROW_NEWBCAST:I = dpp_ctrl 0x150+I (CDNA2+/gfx950). Bit-exact equal to
// __shfl(h, (lane&48)+I, 64) since chains occupy aligned 16-lane rows.
template <int CTRL>
static __device__ __forceinline__ float dpp_bcast(float x) {
  int xi = __float_as_int(x);
  int r = __builtin_amdgcn_update_dpp(xi, xi, CTRL, 0xF, 0xF, false);
  return __int_as_float(r);
}

// ---------------- kernel A: LN1 over C -> xr/xi bf16 [bl][t][c]
__global__ __launch_bounds__(256) void k_ln1(const float* __restrict__ in,
    const float* __restrict__ w, const float* __restrict__ bsh,
    unsigned short* __restrict__ xr, unsigned short* __restrict__ xi, int b0) {
  __shared__ float is[64][101];   // [c][(tloc,ri)]
  __shared__ float os[100][65];   // [(tloc,ri)][c]
  int bid = blockIdx.x;
  int nfl = bid >> 2, tile = bid & 3;         // NB nf-local x 4 tiles of 50 t
  int nf = b0 + nfl;
  int t0 = tile * 50;
  int n = nf / 100, f = nf - n * 100;
  int tid = threadIdx.x;
  for (int i = 0; i < 7; ++i) {               // 64 rows x 25 float4
    int idx = tid + i * 256;
    if (idx < 1600) {
      int c = idx / 25, q = idx - c * 25;
      float4 v = *(const float4*)(in + (size_t)((n * 64 + c) * 100 + f) * 400
                                  + t0 * 2 + q * 4);
      is[c][q*4+0] = v.x; is[c][q*4+1] = v.y; is[c][q*4+2] = v.z; is[c][q*4+3] = v.w;
    }
  }
  __syncthreads();
  if (tid < 100) {
    float s = 0.f, ss = 0.f;
    #pragma unroll
    for (int c = 0; c < 64; ++c) { float v = is[c][tid]; s += v; ss += v * v; }
    float mean = s * 0.015625f;
    float var  = ss * 0.015625f - mean * mean;
    float rstd = rsqrtf(var + 1e-5f);
    #pragma unroll
    for (int c = 0; c < 64; ++c)
      os[tid][c] = (is[c][tid] - mean) * rstd * w[c] + bsh[c];
  }
  __syncthreads();
  for (int ri = 0; ri < 2; ++ri) {
    unsigned short* dst = ri ? xi : xr;
    for (int i = 0; i < 4; ++i) {             // 50 rows x 16 ushort4 per ri
      int idx = tid + i * 256;
      if (idx < 800) {
        int t = idx >> 4, q = idx & 15;
        ushort4 v;
        v.x = f2bfu(os[t*2+ri][q*4+0]); v.y = f2bfu(os[t*2+ri][q*4+1]);
        v.z = f2bfu(os[t*2+ri][q*4+2]); v.w = f2bfu(os[t*2+ri][q*4+3]);
        *(ushort4*)(dst + ((size_t)nfl * 200 + t0 + t) * 64 + q * 4) = v;
      }
    }
  }
}

// ---------------- prep: bihh = bih + bhh ; wbf = bf16(Wih)
__global__ void k_prep(const float* __restrict__ bih, const float* __restrict__ bhh,
                       const float* __restrict__ Wih, float* __restrict__ bihh,
                       unsigned short* __restrict__ wbf) {
  int i = blockIdx.x * 256 + threadIdx.x;
  if (i < 1536) bihh[i] = bih[i] + bhh[i];
  if (i < 98304) wbf[i] = f2bfu(Wih[i]);
}

// ---------------- kernel R: fused input-GEMM + LSTM recurrence (r7 exact).
// 1 wave = 4 chains of the SAME l (grid 24 x ceil(NB/4); dup chains clamp to
// b=NB-1, identical writes). lane = (q=lane>>4 chain, c=lane&15 unit).
// Every 4 steps, MGROUP computes pre-acts via 8 MFMAs:
//   A rows m = b_local*4+dt of x_sel (bf16), B = Wih[l] rows jt*16+c,
//   C = bias splat. D mapping (col=lane&15=unit c, row=q*4+r -> chain q,
//   dt=r) lands each value in its consumer lane. One group pipelined ahead.
// Whh[l] staged in LDS f32x2 wl[2][16][17] (conflict-free broadcast).
// h-broadcast via DPP row_newbcast.
__global__ __launch_bounds__(64) void k_lstm(const unsigned short* __restrict__ xr,
    const unsigned short* __restrict__ xi, const unsigned short* __restrict__ wbf,
    const float* __restrict__ bihh, const float* __restrict__ Whh,
    float* __restrict__ hbuf, int NB, int nbq) {
  __shared__ f32x2 wl[2][16][17];
  int lane = threadIdx.x;
  int q = lane >> 4, c = lane & 15;       // chain-in-block, unit
  int lq = blockIdx.x / nbq, q4 = blockIdx.x - lq * nbq;
  int l = lq;
  int b = q4 * 4 + q; if (b >= NB) b = NB - 1;   // dup chains: identical writes
  const float* Wg = Whh + (size_t)l * 1024;
  for (int idx = lane; idx < 1024; idx += 64) {  // coalesced one-time fill
    int row = idx >> 4, col = idx & 15;
    int gate = row >> 4, kk = row & 15;
    ((float*)&wl[gate >> 1][kk][col])[gate & 1] = Wg[idx];
  }
  __syncthreads();
  const f32x2* wla = wl[0][c];
  const f32x2* wlb = wl[1][c];
  int sel = (0xE54770 >> l) & 1;                 // per-lstm real/imag selection
  const unsigned short* xs = sel ? xi : xr;
  // A-frag source: lane (q,c) holds x row m = c -> b_local=c>>2, dt=c&3.
  int ba = q4 * 4 + (c >> 2); if (ba >= NB) ba = NB - 1;
  const unsigned short* ap2 = xs + ((size_t)ba * 200 + (c & 3)) * 64 + q * 8;
  // B-frag source: Wih row jt*16 + c, channels q*8+e (jt stride 1024 ushorts)
  const unsigned short* wrow = wbf + l * 4096 + c * 64 + q * 8;
  // bias splats (C-operand of first MFMA of each gate)
  float bv0 = bihh[l * 64 + c], bv1 = bihh[l * 64 + 16 + c];
  float bv2 = bihh[l * 64 + 32 + c], bv3 = bihh[l * 64 + 48 + c];
  f32x4 zb0 = {bv0, bv0, bv0, bv0}, zb1 = {bv1, bv1, bv1, bv1};
  f32x4 zb2 = {bv2, bv2, bv2, bv2}, zb3 = {bv3, bv3, bv3, bv3};
  float* hp = hbuf + ((size_t)l * NB + b) * 3200 + c;
  float h = 0.f, cs = 0.f;
  int tcur = 0;
#define MG1(DST, OFS, ZB, A0v, A1v) { \
  bf16x8 w0_ = *(const bf16x8*)(wrow + OFS); \
  bf16x8 w1_ = *(const bf16x8*)(wrow + OFS + 32); \
  f32x4 t_ = __builtin_amdgcn_mfma_f32_16x16x32_bf16(A0v, w0_, ZB, 0, 0, 0); \
  DST = __builtin_amdgcn_mfma_f32_16x16x32_bf16(A1v, w1_, t_, 0, 0, 0); }
#define MGROUP(D0, D1, D2, D3, A0v, A1v) \
  MG1(D0, 0, zb0, A0v, A1v) MG1(D1, 1024, zb1, A0v, A1v) \
  MG1(D2, 2048, zb2, A0v, A1v) MG1(D3, 3072, zb3, A0v, A1v)
#define HV(i) dpp_bcast<0x150 + i>(h)
#define LSTEP2(AC0, AC1, AC2, AC3, FLD) { \
  float hv0  = HV(0),  hv1  = HV(1),  hv2  = HV(2),  hv3  = HV(3);  \
  float hv4  = HV(4),  hv5  = HV(5),  hv6  = HV(6),  hv7  = HV(7);  \
  float hv8  = HV(8),  hv9  = HV(9),  hv10 = HV(10), hv11 = HV(11); \
  float hv12 = HV(12), hv13 = HV(13), hv14 = HV(14), hv15 = HV(15); \
  f32x2 pA = {AC0.FLD, AC1.FLD}; \
  f32x2 qA = {AC2.FLD, AC3.FLD}; \
  f32x2 pB = {0.f, 0.f}, qB = {0.f, 0.f}; \
  pA += wla[0]  * hh2(hv0);  pB += wla[1]  * hh2(hv1);  \
  qA += wlb[0]  * hh2(hv0);  qB += wlb[1]  * hh2(hv1);  \
  pA += wla[2]  * hh2(hv2);  pB += wla[3]  * hh2(hv3);  \
  qA += wlb[2]  * hh2(hv2);  qB += wlb[3]  * hh2(hv3);  \
  pA += wla[4]  * hh2(hv4);  pB += wla[5]  * hh2(hv5);  \
  qA += wlb[4]  * hh2(hv4);  qB += wlb[5]  * hh2(hv5);  \
  pA += wla[6]  * hh2(hv6);  pB += wla[7]  * hh2(hv7);  \
  qA += wlb[6]  * hh2(hv6);  qB += wlb[7]  * hh2(hv7);  \
  pA += wla[8]  * hh2(hv8);  pB += wla[9]  * hh2(hv9);  \
  qA += wlb[8]  * hh2(hv8);  qB += wlb[9]  * hh2(hv9);  \
  pA += wla[10] * hh2(hv10); pB += wla[11] * hh2(hv11); \
  qA += wlb[10] * hh2(hv10); qB += wlb[11] * hh2(hv11); \
  pA += wla[12] * hh2(hv12); pB += wla[13] * hh2(hv13); \
  qA += wlb[12] * hh2(hv12); qB += wlb[13] * hh2(hv13); \
  pA += wla[14] * hh2(hv14); pB += wla[15] * hh2(hv15); \
  qA += wlb[14] * hh2(hv14); qB += wlb[15] * hh2(hv15); \
  f32x2 p01 = pA + pB, p23 = qA + qB; \
  float ig_ = sigf(p01.x), fg_ = sigf(p01.y); \
  float gg_ = tanh_(p23.x), og_ = sigf(p23.y); \
  cs = fg_ * cs + ig_ * gg_; \
  h = og_ * tanh_(cs); \
  hp[tcur * 16] = h; ++tcur; }
  // prologue: group 0 pre-acts; prefetch A of group 1
  bf16x8 a0 = *(const bf16x8*)(ap2), a1 = *(const bf16x8*)(ap2 + 32);
  f32x4 c0, c1, c2, c3, n0, n1, n2, n3;
  MGROUP(c0, c1, c2, c3, a0, a1);
  ap2 += 256;
  a0 = *(const bf16x8*)(ap2); a1 = *(const bf16x8*)(ap2 + 32);
  for (int g = 0; g < 50; ++g) {
    LSTEP2(c0, c1, c2, c3, x)
    LSTEP2(c0, c1, c2, c3, y)
    MGROUP(n0, n1, n2, n3, a0, a1);      // pre-acts for group g+1
    if (g < 48) ap2 += 256;              // A of group g+2 (clamped at end)
    a0 = *(const bf16x8*)(ap2); a1 = *(const bf16x8*)(ap2 + 32);
    LSTEP2(c0, c1, c2, c3, z)
    LSTEP2(c0, c1, c2, c3, w)
    c0 = n0; c1 = n1; c2 = n2; c3 = n3;
  }
#undef LSTEP2
#undef HV
#undef MGROUP
#undef MG1
}

// ---------------- kernel C: attention per (branch, bl), BALANCED pairing.
// Multiplicative causal mask before softmax: masked s get weight exp(0);
// handled via suffix-V init. Threads 2p/2p+1 split row pair (p, 199-p):
// half0 = row p full (p+1 iters) + row 199-p tail s in [100,200-p) (100-p);
// half1 = row 199-p head s in [0,100) (100 iters, kept in REGISTERS).
// Phase 1 (all threads, no divergent barriers) -> ONE uniform __syncthreads()
// -> phase 2: half1 combines LDS partial + register partial, writes row 199-p.
// (r11 ERRATum: barrier inside if/else raced -- wave-level s_barrier with
// unspecified branch order. Fixed by hoisting the barrier.)
__global__ __launch_bounds__(256) void k_attn(const float* __restrict__ hbuf,
                                              float* __restrict__ att, int NB) {
  __shared__ float Q[200][17];
  __shared__ float K[200][16];
  __shared__ float V[200][16];
  __shared__ float Vs[200][17];
  __shared__ float ps[100][17];         // half0's tail partial for row 199-p
  int bid = blockIdx.x;                 // 8 br x NB
  int br = bid / NB, b = bid - br * NB;
  int tid = threadIdx.x;
  const float* qg = hbuf + ((size_t)(br * 3 + 0) * NB + b) * 3200;
  const float* kg = hbuf + ((size_t)(br * 3 + 1) * NB + b) * 3200;
  const float* vg = hbuf + ((size_t)(br * 3 + 2) * NB + b) * 3200;
  for (int i = 0; i < 4; ++i) {         // 200 rows x 4 f4 each of Q,K,V
    int idx = tid + i * 256;
    if (idx < 800) {
      int t = idx >> 2, q = idx & 3;
      float4 a = *(const float4*)(qg + t * 16 + q * 4);
      Q[t][q*4+0] = a.x; Q[t][q*4+1] = a.y; Q[t][q*4+2] = a.z; Q[t][q*4+3] = a.w;
      *(float4*)&K[t][q * 4] = *(const float4*)(kg + t * 16 + q * 4);
      *(float4*)&V[t][q * 4] = *(const float4*)(vg + t * 16 + q * 4);
    }
  }
  __syncthreads();
  if (tid < 16) {                       // suffix sums of V
    float acc = 0.f;
    Vs[199][tid] = 0.f;
    for (int t = 198; t >= 0; --t) { acc += V[t + 1][tid]; Vs[t][tid] = acc; }
  }
  __syncthreads();
  int p = tid >> 1, half = tid & 1;
  int r1 = 199 - p;
  float hva[16];                        // half1's head partial (regs, live
  float hS = 0.f;                       // across the uniform barrier)
  if (tid < 200) {
    if (half == 0) {
      // ---- row p, complete (s in [0,p]) ----
      float q0[16], va[16];
      #pragma unroll
      for (int k = 0; k < 16; ++k) q0[k] = Q[p][k] * 0.25f;
      #pragma unroll
      for (int k = 0; k < 16; ++k) va[k] = Vs[p][k];
      float S = (float)(199 - p);
      for (int s = 0; s <= p; ++s) {
        float e = 0.f;
        #pragma unroll
        for (int k = 0; k < 16; ++k) e += q0[k] * K[s][k];
        float wgt = __expf(e);
        S += wgt;
        #pragma unroll
        for (int k = 0; k < 16; ++k) va[k] += wgt * V[s][k];
      }
      float inv = __fdividef(1.f, S);
      float* dst = att + (((size_t)br * NB + b) * 200 + p) * 16;
      #pragma unroll
      for (int q = 0; q < 4; ++q) {
        float4 v; v.x = va[q*4+0]*inv; v.y = va[q*4+1]*inv;
        v.z = va[q*4+2]*inv; v.w = va[q*4+3]*inv;
        *(float4*)(dst + q * 4) = v;
      }
      // ---- row r1 tail partial: s in [100, 200-p) -> ps[p] ----
      #pragma unroll
      for (int k = 0; k < 16; ++k) q0[k] = Q[r1][k] * 0.25f;
      #pragma unroll
      for (int k = 0; k < 16; ++k) va[k] = 0.f;
      S = 0.f;
      for (int s = 100; s < 200 - p; ++s) {
        float e = 0.f;
        #pragma unroll
        for (int k = 0; k < 16; ++k) e += q0[k] * K[s][k];
        float wgt = __expf(e);
        S += wgt;
        #pragma unroll
        for (int k = 0; k < 16; ++k) va[k] += wgt * V[s][k];
      }
      #pragma unroll
      for (int k = 0; k < 16; ++k) ps[p][k] = va[k];
      ps[p][16] = S;
    } else {
      // ---- row r1 head: s in [0,100), Vs/mask baseline, into registers ----
      float q0[16];
      #pragma unroll
      for (int k = 0; k < 16; ++k) q0[k] = Q[r1][k] * 0.25f;
      #pragma unroll
      for (int k = 0; k < 16; ++k) hva[k] = Vs[r1][k];
      hS = (float)(199 - r1);
      for (int s = 0; s < 100; ++s) {
        float e = 0.f;
        #pragma unroll
        for (int k = 0; k < 16; ++k) e += q0[k] * K[s][k];
        float wgt = __expf(e);
        hS += wgt;
        #pragma unroll
        for (int k = 0; k < 16; ++k) hva[k] += wgt * V[s][k];
      }
    }
  }
  __syncthreads();                      // UNIFORM barrier (all 256 threads)
  if (tid < 200 && half == 1) {
    hS += ps[p][16];
    #pragma unroll
    for (int k = 0; k < 16; ++k) hva[k] += ps[p][k];
    float inv = __fdividef(1.f, hS);
    float* dst = att + (((size_t)br * NB + b) * 200 + r1) * 16;
    #pragma unroll
    for (int q = 0; q < 4; ++q) {
      float4 v; v.x = hva[q*4+0]*inv; v.y = hva[q*4+1]*inv;
      v.z = hva[q*4+2]*inv; v.w = hva[q*4+3]*inv;
      *(float4*)(dst + q * 4) = v;
    }
  }
}

// ---------------- kernel D: combine branches + LN2 + complex linear + LN3 +
// PReLU + residual, with LDS transpose for coalesced [N,C,F,T,2] IO.
__global__ __launch_bounds__(256) void k_out(const float* __restrict__ att,
    const float* __restrict__ in,
    const float* __restrict__ ln2w, const float* __restrict__ ln2b,
    const float* __restrict__ lrw, const float* __restrict__ lrb,
    const float* __restrict__ liw, const float* __restrict__ lib,
    const float* __restrict__ ln3w, const float* __restrict__ ln3b,
    const float* __restrict__ pa, float* __restrict__ out, int b0, int NB) {
  __shared__ float as_[8][40][17];
  __shared__ float ys[40][2][17];
  __shared__ float zs[64][81];
  int bid = blockIdx.x;                 // NB nf-local x 5 tiles of 40 t
  int nfl = bid / 5, tile = bid - nfl * 5;
  int nf = b0 + nfl;
  int t0 = tile * 40;
  int n = nf / 100, f = nf - n * 100;
  int tid = threadIdx.x;
  for (int i = 0; i < 5; ++i) {         // att: 8 br x 40 t x 4 f4
    int idx = tid + i * 256;
    int br = idx / 160, r = idx - br * 160;
    int t = r >> 2, q = r & 3;
    float4 v = *(const float4*)(att + (((size_t)br * NB + nfl) * 200 + t0 + t) * 16 + q * 4);
    as_[br][t][q*4+0] = v.x; as_[br][t][q*4+1] = v.y;
    as_[br][t][q*4+2] = v.z; as_[br][t][q*4+3] = v.w;
  }
  __syncthreads();
  if (tid < 80) {                       // combine + LN2 per (t,ri)
    int t = tid >> 1, ri = tid & 1;
    float vv[16]; float s = 0.f, ss = 0.f;
    #pragma unroll
    for (int k = 0; k < 16; ++k) {
      float v;
      if (ri == 0) v = as_[0][t][k] - as_[1][t][k] - as_[2][t][k] - as_[3][t][k];
      else         v = as_[4][t][k] + as_[5][t][k] + as_[6][t][k] - as_[7][t][k];
      vv[k] = v; s += v; ss += v * v;
    }
    float mean = s * 0.0625f;
    float var  = ss * 0.0625f - mean * mean;
    float rstd = rsqrtf(var + 1e-5f);
    #pragma unroll
    for (int k = 0; k < 16; ++k)
      ys[t][ri][k] = (vv[k] - mean) * rstd * ln2w[k] + ln2b[k];
  }
  __syncthreads();
  // complex linear 16->64 + LN3 over c (wave = 64 lanes = c) + PReLU
  int wv = tid >> 6, cc = tid & 63;
  float lr[16], li[16];
  #pragma unroll
  for (int q = 0; q < 4; ++q) {
    float4 v = *(const float4*)(lrw + cc * 16 + q * 4);
    lr[q*4+0] = v.x; lr[q*4+1] = v.y; lr[q*4+2] = v.z; lr[q*4+3] = v.w;
    float4 u = *(const float4*)(liw + cc * 16 + q * 4);
    li[q*4+0] = u.x; li[q*4+1] = u.y; li[q*4+2] = u.z; li[q*4+3] = u.w;
  }
  float brc = lrb[cc], bic = lib[cc];
  float w3 = ln3w[cc], b3 = ln3b[cc];
  float aP = pa[0];
  for (int tt = wv; tt < 40; tt += 4) {
    float zr = brc - bic, zi = brc + bic;
    #pragma unroll
    for (int k = 0; k < 16; ++k) {
      float yr = ys[tt][0][k], yi = ys[tt][1][k];
      zr += yr * lr[k] - yi * li[k];
      zi += yi * lr[k] + yr * li[k];
    }
    float s1 = zr, s2 = zr * zr, s3 = zi, s4 = zi * zi;
    #pragma unroll
    for (int m = 1; m < 64; m <<= 1) {
      s1 += __shfl_xor(s1, m, 64);
      s2 += __shfl_xor(s2, m, 64);
      s3 += __shfl_xor(s3, m, 64);
      s4 += __shfl_xor(s4, m, 64);
    }
    float mr = s1 * 0.015625f, vr = s2 * 0.015625f - mr * mr;
    float mi = s3 * 0.015625f, vi = s4 * 0.015625f - mi * mi;
    float r1 = (zr - mr) * rsqrtf(vr + 1e-5f) * w3 + b3;
    float r2 = (zi - mi) * rsqrtf(vi + 1e-5f) * w3 + b3;
    r1 = r1 >= 0.f ? r1 : aP * r1;
    r2 = r2 >= 0.f ? r2 : aP * r2;
    zs[cc][tt * 2 + 0] = r1;
    zs[cc][tt * 2 + 1] = r2;
  }
  __syncthreads();
  for (int i = 0; i < 5; ++i) {         // residual + coalesced write
    int idx = tid + i * 256;            // 64 c x 20 f4
    int c = idx / 20, q = idx - c * 20;
    size_t gaddr = (size_t)((n * 64 + c) * 100 + f) * 400 + t0 * 2 + q * 4;
    float4 v = *(const float4*)(in + gaddr);
    float4 z;
    z.x = zs[c][q*4+0] + v.x; z.y = zs[c][q*4+1] + v.y;
    z.z = zs[c][q*4+2] + v.z; z.w = zs[c][q*4+3] + v.w;
    *(float4*)(out + gaddr) = z;
  }
}

extern "C" void kernel_launch(void* const* d_in, const int* in_sizes, int n_in,
                              void* d_out, int out_size, void* d_ws, size_t ws_size,
                              hipStream_t stream) {
  (void)in_sizes; (void)n_in; (void)out_size;
  const float* inputs = (const float*)d_in[0];
  const float* Wih  = (const float*)d_in[1];
  const float* Whh  = (const float*)d_in[2];
  const float* bih  = (const float*)d_in[3];
  const float* bhh  = (const float*)d_in[4];
  const float* ln1w = (const float*)d_in[5];
  const float* ln1b = (const float*)d_in[6];
  const float* ln2w = (const float*)d_in[7];
  const float* ln2b = (const float*)d_in[8];
  const float* lrw  = (const float*)d_in[9];
  const float* lrb  = (const float*)d_in[10];
  const float* liw  = (const float*)d_in[11];
  const float* lib  = (const float*)d_in[12];
  const float* ln3w = (const float*)d_in[13];
  const float* ln3b = (const float*)d_in[14];
  const float* pa   = (const float*)d_in[15];
  float* out = (float*)d_out;
  char* ws = (char*)d_ws;

  // pick largest chunk NB (400,200,100,50,25) whose buffers fit ws_size
  // per-b: xr+xi 51200 + h 307200 + att 102400 = 460800 B
  int NB = 400;
  while (NB > 25 && 204800ull + (size_t)NB * 460800ull > ws_size) NB /= 2;
  int nch = 400 / NB;

  float* bihh = (float*)(ws + 0);                        // 6 KB
  unsigned short* wbf = (unsigned short*)(ws + 8192);    // 192 KB bf16 Wih
  size_t o_xr = 204800;
  size_t o_xi = o_xr + (size_t)NB * 25600;
  size_t o_h  = o_xi + (size_t)NB * 25600;
  size_t o_at = o_h  + (size_t)NB * 307200;
  unsigned short* xr = (unsigned short*)(ws + o_xr);
  unsigned short* xi = (unsigned short*)(ws + o_xi);
  float* hbuf = (float*)(ws + o_h);
  float* att  = (float*)(ws + o_at);

  k_prep<<<384, 256, 0, stream>>>(bih, bhh, Wih, bihh, wbf);
  int nbq = (NB + 3) >> 2;              // 4-chain groups per l
  for (int ch = 0; ch < nch; ++ch) {
    int b0 = ch * NB;
    k_ln1 <<<NB * 4,   256, 0, stream>>>(inputs, ln1w, ln1b, xr, xi, b0);
    k_lstm<<<24 * nbq,  64, 0, stream>>>(xr, xi, wbf, bihh, Whh, hbuf, NB, nbq);
    k_attn<<<8 * NB,   256, 0, stream>>>(hbuf, att, NB);
    k_out <<<NB * 5,   256, 0, stream>>>(att, inputs, ln2w, ln2b, lrw, lrb,
                                         liw, lib, ln3w, ln3b, pa, out, b0, NB);
  }
}

// Round 13
// 489.924 us; speedup vs baseline: 1.2227x; 1.2227x over previous
//
#include <hip/hip_runtime.h>
#include <hip/hip_bf16.h>

// Problem: N=4,C=64,F=100,T=200,H=16 ; B=N*F=400, BT=80000
// r13: k_attn balanced pairing, done right. r12's version passed (absmax
// 0.03125 proved the head/tail reassociation) but regressed to 278us from
// TWO mistakes: (1) tid&1 split -> both halves in every wave -> if/else
// serialized (804 iter-units/block vs original 584) + broken lockstep
// K/V broadcast (934K bank conflicts); (2) extra ps[100][17] LDS pushed
// 52.8->59.9KB -> 3->2 blocks/CU. Fix: half = tid>>7 (wave-uniform branch),
// lockstep s in every loop (broadcast reads), and tail partials go through
// the Vs[0..99] rows (reused after a uniform barrier; half1 only reads
// Vs rows >=100) -> zero extra LDS, 3 blocks/CU. Iteration sum 500/block.
// k_lstm = r7 exact (best measured 197us: fused MFMA input-GEMM+recurrence,
// LDS weights, DPP h-broadcast; r8/r9/r10 alternatives all neutral-or-worse).
// Pipeline per chunk: ln1 (fp32->bf16 xr/xi) -> k_lstm -> attention (mult.
// causal mask BEFORE softmax, suffix-V, balanced wave-uniform pairing) ->
// combine+LN2+complex linear+LN3+PReLU+residual.
// ws: header 204800 B (bihh fp32 @0, Wih-bf16 @8192), then per chunk:
//   xr bf16 [NB][200][64], xi same, h f32 [24][NB][200][16],
//   att f32 [8][NB][200][16].  Total = 204800 + NB*460800.

typedef __attribute__((ext_vector_type(8))) short bf16x8;
typedef __attribute__((ext_vector_type(4))) float f32x4;
typedef __attribute__((ext_vector_type(2))) float f32x2;

static __device__ __forceinline__ float bf2f(unsigned short u) {
  return __uint_as_float(((unsigned)u) << 16);
}
static __device__ __forceinline__ unsigned short f2bfu(float x) {
  __hip_bfloat16 h = __float2bfloat16(x);
  return *(unsigned short*)&h;
}
static __device__ __forceinline__ float sigf(float x) {
  return __fdividef(1.f, 1.f + __expf(-x));
}
static __device__ __forceinline__ float tanh_(float x) {
  return 1.f - __fdividef(2.f, __expf(2.f * x) + 1.f);  // safe at +-inf
}
static __device__ __forceinline__ f32x2 hh2(float v) {
  f32x2 r; r.x = v; r.y = v; return r;
}

// Broadcast lane (row-base + I) of h to all 16 lanes of its row.
// ROW_NEWBCAST:I = dpp_ctrl 0x150+I (CDNA2+/gfx950). Bit-exact equal to
// __shfl(h, (lane&48)+I, 64) since chains occupy aligned 16-lane rows.
template <int CTRL>
static __device__ __forceinline__ float dpp_bcast(float x) {
  int xi = __float_as_int(x);
  int r = __builtin_amdgcn_update_dpp(xi, xi, CTRL, 0xF, 0xF, false);
  return __int_as_float(r);
}

// ---------------- kernel A: LN1 over C -> xr/xi bf16 [bl][t][c]
__global__ __launch_bounds__(256) void k_ln1(const float* __restrict__ in,
    const float* __restrict__ w, const float* __restrict__ bsh,
    unsigned short* __restrict__ xr, unsigned short* __restrict__ xi, int b0) {
  __shared__ float is[64][101];   // [c][(tloc,ri)]
  __shared__ float os[100][65];   // [(tloc,ri)][c]
  int bid = blockIdx.x;
  int nfl = bid >> 2, tile = bid & 3;         // NB nf-local x 4 tiles of 50 t
  int nf = b0 + nfl;
  int t0 = tile * 50;
  int n = nf / 100, f = nf - n * 100;
  int tid = threadIdx.x;
  for (int i = 0; i < 7; ++i) {               // 64 rows x 25 float4
    int idx = tid + i * 256;
    if (idx < 1600) {
      int c = idx / 25, q = idx - c * 25;
      float4 v = *(const float4*)(in + (size_t)((n * 64 + c) * 100 + f) * 400
                                  + t0 * 2 + q * 4);
      is[c][q*4+0] = v.x; is[c][q*4+1] = v.y; is[c][q*4+2] = v.z; is[c][q*4+3] = v.w;
    }
  }
  __syncthreads();
  if (tid < 100) {
    float s = 0.f, ss = 0.f;
    #pragma unroll
    for (int c = 0; c < 64; ++c) { float v = is[c][tid]; s += v; ss += v * v; }
    float mean = s * 0.015625f;
    float var  = ss * 0.015625f - mean * mean;
    float rstd = rsqrtf(var + 1e-5f);
    #pragma unroll
    for (int c = 0; c < 64; ++c)
      os[tid][c] = (is[c][tid] - mean) * rstd * w[c] + bsh[c];
  }
  __syncthreads();
  for (int ri = 0; ri < 2; ++ri) {
    unsigned short* dst = ri ? xi : xr;
    for (int i = 0; i < 4; ++i) {             // 50 rows x 16 ushort4 per ri
      int idx = tid + i * 256;
      if (idx < 800) {
        int t = idx >> 4, q = idx & 15;
        ushort4 v;
        v.x = f2bfu(os[t*2+ri][q*4+0]); v.y = f2bfu(os[t*2+ri][q*4+1]);
        v.z = f2bfu(os[t*2+ri][q*4+2]); v.w = f2bfu(os[t*2+ri][q*4+3]);
        *(ushort4*)(dst + ((size_t)nfl * 200 + t0 + t) * 64 + q * 4) = v;
      }
    }
  }
}

// ---------------- prep: bihh = bih + bhh ; wbf = bf16(Wih)
__global__ void k_prep(const float* __restrict__ bih, const float* __restrict__ bhh,
                       const float* __restrict__ Wih, float* __restrict__ bihh,
                       unsigned short* __restrict__ wbf) {
  int i = blockIdx.x * 256 + threadIdx.x;
  if (i < 1536) bihh[i] = bih[i] + bhh[i];
  if (i < 98304) wbf[i] = f2bfu(Wih[i]);
}

// ---------------- kernel R: fused input-GEMM + LSTM recurrence (r7 exact).
// 1 wave = 4 chains of the SAME l (grid 24 x ceil(NB/4); dup chains clamp to
// b=NB-1, identical writes). lane = (q=lane>>4 chain, c=lane&15 unit).
// Every 4 steps, MGROUP computes pre-acts via 8 MFMAs:
//   A rows m = b_local*4+dt of x_sel (bf16), B = Wih[l] rows jt*16+c,
//   C = bias splat. D mapping (col=lane&15=unit c, row=q*4+r -> chain q,
//   dt=r) lands each value in its consumer lane. One group pipelined ahead.
// Whh[l] staged in LDS f32x2 wl[2][16][17] (conflict-free broadcast).
// h-broadcast via DPP row_newbcast.
__global__ __launch_bounds__(64) void k_lstm(const unsigned short* __restrict__ xr,
    const unsigned short* __restrict__ xi, const unsigned short* __restrict__ wbf,
    const float* __restrict__ bihh, const float* __restrict__ Whh,
    float* __restrict__ hbuf, int NB, int nbq) {
  __shared__ f32x2 wl[2][16][17];
  int lane = threadIdx.x;
  int q = lane >> 4, c = lane & 15;       // chain-in-block, unit
  int lq = blockIdx.x / nbq, q4 = blockIdx.x - lq * nbq;
  int l = lq;
  int b = q4 * 4 + q; if (b >= NB) b = NB - 1;   // dup chains: identical writes
  const float* Wg = Whh + (size_t)l * 1024;
  for (int idx = lane; idx < 1024; idx += 64) {  // coalesced one-time fill
    int row = idx >> 4, col = idx & 15;
    int gate = row >> 4, kk = row & 15;
    ((float*)&wl[gate >> 1][kk][col])[gate & 1] = Wg[idx];
  }
  __syncthreads();
  const f32x2* wla = wl[0][c];
  const f32x2* wlb = wl[1][c];
  int sel = (0xE54770 >> l) & 1;                 // per-lstm real/imag selection
  const unsigned short* xs = sel ? xi : xr;
  // A-frag source: lane (q,c) holds x row m = c -> b_local=c>>2, dt=c&3.
  int ba = q4 * 4 + (c >> 2); if (ba >= NB) ba = NB - 1;
  const unsigned short* ap2 = xs + ((size_t)ba * 200 + (c & 3)) * 64 + q * 8;
  // B-frag source: Wih row jt*16 + c, channels q*8+e (jt stride 1024 ushorts)
  const unsigned short* wrow = wbf + l * 4096 + c * 64 + q * 8;
  // bias splats (C-operand of first MFMA of each gate)
  float bv0 = bihh[l * 64 + c], bv1 = bihh[l * 64 + 16 + c];
  float bv2 = bihh[l * 64 + 32 + c], bv3 = bihh[l * 64 + 48 + c];
  f32x4 zb0 = {bv0, bv0, bv0, bv0}, zb1 = {bv1, bv1, bv1, bv1};
  f32x4 zb2 = {bv2, bv2, bv2, bv2}, zb3 = {bv3, bv3, bv3, bv3};
  float* hp = hbuf + ((size_t)l * NB + b) * 3200 + c;
  float h = 0.f, cs = 0.f;
  int tcur = 0;
#define MG1(DST, OFS, ZB, A0v, A1v) { \
  bf16x8 w0_ = *(const bf16x8*)(wrow + OFS); \
  bf16x8 w1_ = *(const bf16x8*)(wrow + OFS + 32); \
  f32x4 t_ = __builtin_amdgcn_mfma_f32_16x16x32_bf16(A0v, w0_, ZB, 0, 0, 0); \
  DST = __builtin_amdgcn_mfma_f32_16x16x32_bf16(A1v, w1_, t_, 0, 0, 0); }
#define MGROUP(D0, D1, D2, D3, A0v, A1v) \
  MG1(D0, 0, zb0, A0v, A1v) MG1(D1, 1024, zb1, A0v, A1v) \
  MG1(D2, 2048, zb2, A0v, A1v) MG1(D3, 3072, zb3, A0v, A1v)
#define HV(i) dpp_bcast<0x150 + i>(h)
#define LSTEP2(AC0, AC1, AC2, AC3, FLD) { \
  float hv0  = HV(0),  hv1  = HV(1),  hv2  = HV(2),  hv3  = HV(3);  \
  float hv4  = HV(4),  hv5  = HV(5),  hv6  = HV(6),  hv7  = HV(7);  \
  float hv8  = HV(8),  hv9  = HV(9),  hv10 = HV(10), hv11 = HV(11); \
  float hv12 = HV(12), hv13 = HV(13), hv14 = HV(14), hv15 = HV(15); \
  f32x2 pA = {AC0.FLD, AC1.FLD}; \
  f32x2 qA = {AC2.FLD, AC3.FLD}; \
  f32x2 pB = {0.f, 0.f}, qB = {0.f, 0.f}; \
  pA += wla[0]  * hh2(hv0);  pB += wla[1]  * hh2(hv1);  \
  qA += wlb[0]  * hh2(hv0);  qB += wlb[1]  * hh2(hv1);  \
  pA += wla[2]  * hh2(hv2);  pB += wla[3]  * hh2(hv3);  \
  qA += wlb[2]  * hh2(hv2);  qB += wlb[3]  * hh2(hv3);  \
  pA += wla[4]  * hh2(hv4);  pB += wla[5]  * hh2(hv5);  \
  qA += wlb[4]  * hh2(hv4);  qB += wlb[5]  * hh2(hv5);  \
  pA += wla[6]  * hh2(hv6);  pB += wla[7]  * hh2(hv7);  \
  qA += wlb[6]  * hh2(hv6);  qB += wlb[7]  * hh2(hv7);  \
  pA += wla[8]  * hh2(hv8);  pB += wla[9]  * hh2(hv9);  \
  qA += wlb[8]  * hh2(hv8);  qB += wlb[9]  * hh2(hv9);  \
  pA += wla[10] * hh2(hv10); pB += wla[11] * hh2(hv11); \
  qA += wlb[10] * hh2(hv10); qB += wlb[11] * hh2(hv11); \
  pA += wla[12] * hh2(hv12); pB += wla[13] * hh2(hv13); \
  qA += wlb[12] * hh2(hv12); qB += wlb[13] * hh2(hv13); \
  pA += wla[14] * hh2(hv14); pB += wla[15] * hh2(hv15); \
  qA += wlb[14] * hh2(hv14); qB += wlb[15] * hh2(hv15); \
  f32x2 p01 = pA + pB, p23 = qA + qB; \
  float ig_ = sigf(p01.x), fg_ = sigf(p01.y); \
  float gg_ = tanh_(p23.x), og_ = sigf(p23.y); \
  cs = fg_ * cs + ig_ * gg_; \
  h = og_ * tanh_(cs); \
  hp[tcur * 16] = h; ++tcur; }
  // prologue: group 0 pre-acts; prefetch A of group 1
  bf16x8 a0 = *(const bf16x8*)(ap2), a1 = *(const bf16x8*)(ap2 + 32);
  f32x4 c0, c1, c2, c3, n0, n1, n2, n3;
  MGROUP(c0, c1, c2, c3, a0, a1);
  ap2 += 256;
  a0 = *(const bf16x8*)(ap2); a1 = *(const bf16x8*)(ap2 + 32);
  for (int g = 0; g < 50; ++g) {
    LSTEP2(c0, c1, c2, c3, x)
    LSTEP2(c0, c1, c2, c3, y)
    MGROUP(n0, n1, n2, n3, a0, a1);      // pre-acts for group g+1
    if (g < 48) ap2 += 256;              // A of group g+2 (clamped at end)
    a0 = *(const bf16x8*)(ap2); a1 = *(const bf16x8*)(ap2 + 32);
    LSTEP2(c0, c1, c2, c3, z)
    LSTEP2(c0, c1, c2, c3, w)
    c0 = n0; c1 = n1; c2 = n2; c3 = n3;
  }
#undef LSTEP2
#undef HV
#undef MGROUP
#undef MG1
}

// ---------------- kernel C: attention per (branch, bl), balanced pairing
// with WAVE-UNIFORM halves. Multiplicative causal mask before softmax:
// masked s get weight exp(0); handled via suffix-V init.
// half = tid>>7 (waves 0-1 vs 2-3), p = tid&127, active p<100, r1 = 199-p.
//   half0: row p complete (s in [0,p]) -> att; tail of row r1
//          (s in [100, 200-p)) -> registers.
//   half1: head of row r1 (s in [0,100)) + Vs/mask baseline -> registers.
// Uniform barrier; half0 stores tail partials into Vs[0..99] (rows <100 are
// only read by half0 itself in phase 1 -- safe to reuse, zero extra LDS so
// 3 blocks/CU is preserved); uniform barrier; half1 combines + writes r1.
// Every loop advances s in lockstep across the wave -> K/V reads broadcast
// (r12's 934K conflicts came from the tid&1 intra-wave divergent split).
__global__ __launch_bounds__(256) void k_attn(const float* __restrict__ hbuf,
                                              float* __restrict__ att, int NB) {
  __shared__ float Q[200][17];
  __shared__ float K[200][16];
  __shared__ float V[200][16];
  __shared__ float Vs[200][17];   // suffix sums; rows 0..99 reused for partials
  int bid = blockIdx.x;                 // 8 br x NB
  int br = bid / NB, b = bid - br * NB;
  int tid = threadIdx.x;
  const float* qg = hbuf + ((size_t)(br * 3 + 0) * NB + b) * 3200;
  const float* kg = hbuf + ((size_t)(br * 3 + 1) * NB + b) * 3200;
  const float* vg = hbuf + ((size_t)(br * 3 + 2) * NB + b) * 3200;
  for (int i = 0; i < 4; ++i) {         // 200 rows x 4 f4 each of Q,K,V
    int idx = tid + i * 256;
    if (idx < 800) {
      int t = idx >> 2, q = idx & 3;
      float4 a = *(const float4*)(qg + t * 16 + q * 4);
      Q[t][q*4+0] = a.x; Q[t][q*4+1] = a.y; Q[t][q*4+2] = a.z; Q[t][q*4+3] = a.w;
      *(float4*)&K[t][q * 4] = *(const float4*)(kg + t * 16 + q * 4);
      *(float4*)&V[t][q * 4] = *(const float4*)(vg + t * 16 + q * 4);
    }
  }
  __syncthreads();
  if (tid < 16) {                       // suffix sums of V
    float acc = 0.f;
    Vs[199][tid] = 0.f;
    for (int t = 198; t >= 0; --t) { acc += V[t + 1][tid]; Vs[t][tid] = acc; }
  }
  __syncthreads();
  int half = tid >> 7, p = tid & 127;
  bool act = p < 100;
  int r1 = 199 - p;
  float ava[16];                        // partial (tail for half0, head for half1)
  float aS = 0.f;
  if (act) {
    if (half == 0) {
      // ---- row p, complete (s in [0,p]) ----
      float q0[16], va[16];
      #pragma unroll
      for (int k = 0; k < 16; ++k) q0[k] = Q[p][k] * 0.25f;   // fold /sqrt(16)
      #pragma unroll
      for (int k = 0; k < 16; ++k) va[k] = Vs[p][k];
      float S = (float)(199 - p);
      for (int s = 0; s <= p; ++s) {
        float e = 0.f;
        #pragma unroll
        for (int k = 0; k < 16; ++k) e += q0[k] * K[s][k];
        float wgt = __expf(e);
        S += wgt;
        #pragma unroll
        for (int k = 0; k < 16; ++k) va[k] += wgt * V[s][k];
      }
      float inv = __fdividef(1.f, S);
      float* dst = att + (((size_t)br * NB + b) * 200 + p) * 16;
      #pragma unroll
      for (int q = 0; q < 4; ++q) {
        float4 v; v.x = va[q*4+0]*inv; v.y = va[q*4+1]*inv;
        v.z = va[q*4+2]*inv; v.w = va[q*4+3]*inv;
        *(float4*)(dst + q * 4) = v;
      }
      // ---- row r1 tail partial: s in [100, 200-p) -> registers ----
      #pragma unroll
      for (int k = 0; k < 16; ++k) q0[k] = Q[r1][k] * 0.25f;
      #pragma unroll
      for (int k = 0; k < 16; ++k) ava[k] = 0.f;
      for (int s = 100; s < 200 - p; ++s) {
        float e = 0.f;
        #pragma unroll
        for (int k = 0; k < 16; ++k) e += q0[k] * K[s][k];
        float wgt = __expf(e);
        aS += wgt;
        #pragma unroll
        for (int k = 0; k < 16; ++k) ava[k] += wgt * V[s][k];
      }
    } else {
      // ---- row r1 head: s in [0,100), Vs/mask baseline, registers ----
      float q0[16];
      #pragma unroll
      for (int k = 0; k < 16; ++k) q0[k] = Q[r1][k] * 0.25f;
      #pragma unroll
      for (int k = 0; k < 16; ++k) ava[k] = Vs[r1][k];
      aS = (float)(199 - r1);
      for (int s = 0; s < 100; ++s) {
        float e = 0.f;
        #pragma unroll
        for (int k = 0; k < 16; ++k) e += q0[k] * K[s][k];
        float wgt = __expf(e);
        aS += wgt;
        #pragma unroll
        for (int k = 0; k < 16; ++k) ava[k] += wgt * V[s][k];
      }
    }
  }
  __syncthreads();                      // UNIFORM: all phase-1 Vs reads done
  if (act && half == 0) {               // reuse Vs rows 0..99 for tail partials
    #pragma unroll
    for (int k = 0; k < 16; ++k) Vs[p][k] = ava[k];
    Vs[p][16] = aS;
  }
  __syncthreads();                      // UNIFORM
  if (act && half == 1) {
    aS += Vs[p][16];
    #pragma unroll
    for (int k = 0; k < 16; ++k) ava[k] += Vs[p][k];
    float inv = __fdividef(1.f, aS);
    float* dst = att + (((size_t)br * NB + b) * 200 + r1) * 16;
    #pragma unroll
    for (int q = 0; q < 4; ++q) {
      float4 v; v.x = ava[q*4+0]*inv; v.y = ava[q*4+1]*inv;
      v.z = ava[q*4+2]*inv; v.w = ava[q*4+3]*inv;
      *(float4*)(dst + q * 4) = v;
    }
  }
}

// ---------------- kernel D: combine branches + LN2 + complex linear + LN3 +
// PReLU + residual, with LDS transpose for coalesced [N,C,F,T,2] IO.
__global__ __launch_bounds__(256) void k_out(const float* __restrict__ att,
    const float* __restrict__ in,
    const float* __restrict__ ln2w, const float* __restrict__ ln2b,
    const float* __restrict__ lrw, const float* __restrict__ lrb,
    const float* __restrict__ liw, const float* __restrict__ lib,
    const float* __restrict__ ln3w, const float* __restrict__ ln3b,
    const float* __restrict__ pa, float* __restrict__ out, int b0, int NB) {
  __shared__ float as_[8][40][17];
  __shared__ float ys[40][2][17];
  __shared__ float zs[64][81];
  int bid = blockIdx.x;                 // NB nf-local x 5 tiles of 40 t
  int nfl = bid / 5, tile = bid - nfl * 5;
  int nf = b0 + nfl;
  int t0 = tile * 40;
  int n = nf / 100, f = nf - n * 100;
  int tid = threadIdx.x;
  for (int i = 0; i < 5; ++i) {         // att: 8 br x 40 t x 4 f4
    int idx = tid + i * 256;
    int br = idx / 160, r = idx - br * 160;
    int t = r >> 2, q = r & 3;
    float4 v = *(const float4*)(att + (((size_t)br * NB + nfl) * 200 + t0 + t) * 16 + q * 4);
    as_[br][t][q*4+0] = v.x; as_[br][t][q*4+1] = v.y;
    as_[br][t][q*4+2] = v.z; as_[br][t][q*4+3] = v.w;
  }
  __syncthreads();
  if (tid < 80) {                       // combine + LN2 per (t,ri)
    int t = tid >> 1, ri = tid & 1;
    float vv[16]; float s = 0.f, ss = 0.f;
    #pragma unroll
    for (int k = 0; k < 16; ++k) {
      float v;
      if (ri == 0) v = as_[0][t][k] - as_[1][t][k] - as_[2][t][k] - as_[3][t][k];
      else         v = as_[4][t][k] + as_[5][t][k] + as_[6][t][k] - as_[7][t][k];
      vv[k] = v; s += v; ss += v * v;
    }
    float mean = s * 0.0625f;
    float var  = ss * 0.0625f - mean * mean;
    float rstd = rsqrtf(var + 1e-5f);
    #pragma unroll
    for (int k = 0; k < 16; ++k)
      ys[t][ri][k] = (vv[k] - mean) * rstd * ln2w[k] + ln2b[k];
  }
  __syncthreads();
  // complex linear 16->64 + LN3 over c (wave = 64 lanes = c) + PReLU
  int wv = tid >> 6, cc = tid & 63;
  float lr[16], li[16];
  #pragma unroll
  for (int q = 0; q < 4; ++q) {
    float4 v = *(const float4*)(lrw + cc * 16 + q * 4);
    lr[q*4+0] = v.x; lr[q*4+1] = v.y; lr[q*4+2] = v.z; lr[q*4+3] = v.w;
    float4 u = *(const float4*)(liw + cc * 16 + q * 4);
    li[q*4+0] = u.x; li[q*4+1] = u.y; li[q*4+2] = u.z; li[q*4+3] = u.w;
  }
  float brc = lrb[cc], bic = lib[cc];
  float w3 = ln3w[cc], b3 = ln3b[cc];
  float aP = pa[0];
  for (int tt = wv; tt < 40; tt += 4) {
    float zr = brc - bic, zi = brc + bic;
    #pragma unroll
    for (int k = 0; k < 16; ++k) {
      float yr = ys[tt][0][k], yi = ys[tt][1][k];
      zr += yr * lr[k] - yi * li[k];
      zi += yi * lr[k] + yr * li[k];
    }
    float s1 = zr, s2 = zr * zr, s3 = zi, s4 = zi * zi;
    #pragma unroll
    for (int m = 1; m < 64; m <<= 1) {
      s1 += __shfl_xor(s1, m, 64);
      s2 += __shfl_xor(s2, m, 64);
      s3 += __shfl_xor(s3, m, 64);
      s4 += __shfl_xor(s4, m, 64);
    }
    float mr = s1 * 0.015625f, vr = s2 * 0.015625f - mr * mr;
    float mi = s3 * 0.015625f, vi = s4 * 0.015625f - mi * mi;
    float r1 = (zr - mr) * rsqrtf(vr + 1e-5f) * w3 + b3;
    float r2 = (zi - mi) * rsqrtf(vi + 1e-5f) * w3 + b3;
    r1 = r1 >= 0.f ? r1 : aP * r1;
    r2 = r2 >= 0.f ? r2 : aP * r2;
    zs[cc][tt * 2 + 0] = r1;
    zs[cc][tt * 2 + 1] = r2;
  }
  __syncthreads();
  for (int i = 0; i < 5; ++i) {         // residual + coalesced write
    int idx = tid + i * 256;            // 64 c x 20 f4
    int c = idx / 20, q = idx - c * 20;
    size_t gaddr = (size_t)((n * 64 + c) * 100 + f) * 400 + t0 * 2 + q * 4;
    float4 v = *(const float4*)(in + gaddr);
    float4 z;
    z.x = zs[c][q*4+0] + v.x; z.y = zs[c][q*4+1] + v.y;
    z.z = zs[c][q*4+2] + v.z; z.w = zs[c][q*4+3] + v.w;
    *(float4*)(out + gaddr) = z;
  }
}

extern "C" void kernel_launch(void* const* d_in, const int* in_sizes, int n_in,
                              void* d_out, int out_size, void* d_ws, size_t ws_size,
                              hipStream_t stream) {
  (void)in_sizes; (void)n_in; (void)out_size;
  const float* inputs = (const float*)d_in[0];
  const float* Wih  = (const float*)d_in[1];
  const float* Whh  = (const float*)d_in[2];
  const float* bih  = (const float*)d_in[3];
  const float* bhh  = (const float*)d_in[4];
  const float* ln1w = (const float*)d_in[5];
  const float* ln1b = (const float*)d_in[6];
  const float* ln2w = (const float*)d_in[7];
  const float* ln2b = (const float*)d_in[8];
  const float* lrw  = (const float*)d_in[9];
  const float* lrb  = (const float*)d_in[10];
  const float* liw  = (const float*)d_in[11];
  const float* lib  = (const float*)d_in[12];
  const float* ln3w = (const float*)d_in[13];
  const float* ln3b = (const float*)d_in[14];
  const float* pa   = (const float*)d_in[15];
  float* out = (float*)d_out;
  char* ws = (char*)d_ws;

  // pick largest chunk NB (400,200,100,50,25) whose buffers fit ws_size
  // per-b: xr+xi 51200 + h 307200 + att 102400 = 460800 B
  int NB = 400;
  while (NB > 25 && 204800ull + (size_t)NB * 460800ull > ws_size) NB /= 2;
  int nch = 400 / NB;

  float* bihh = (float*)(ws + 0);                        // 6 KB
  unsigned short* wbf = (unsigned short*)(ws + 8192);    // 192 KB bf16 Wih
  size_t o_xr = 204800;
  size_t o_xi = o_xr + (size_t)NB * 25600;
  size_t o_h  = o_xi + (size_t)NB * 25600;
  size_t o_at = o_h  + (size_t)NB * 307200;
  unsigned short* xr = (unsigned short*)(ws + o_xr);
  unsigned short* xi = (unsigned short*)(ws + o_xi);
  float* hbuf = (float*)(ws + o_h);
  float* att  = (float*)(ws + o_at);

  k_prep<<<384, 256, 0, stream>>>(bih, bhh, Wih, bihh, wbf);
  int nbq = (NB + 3) >> 2;              // 4-chain groups per l
  for (int ch = 0; ch < nch; ++ch) {
    int b0 = ch * NB;
    k_ln1 <<<NB * 4,   256, 0, stream>>>(inputs, ln1w, ln1b, xr, xi, b0);
    k_lstm<<<24 * nbq,  64, 0, stream>>>(xr, xi, wbf, bihh, Whh, hbuf, NB, nbq);
    k_attn<<<8 * NB,   256, 0, stream>>>(hbuf, att, NB);
    k_out <<<NB * 5,   256, 0, stream>>>(att, inputs, ln2w, ln2b, lrw, lrb,
                                         liw, lib, ln3w, ln3b, pa, out, b0, NB);
  }
}

// Round 14
// 420.742 us; speedup vs baseline: 1.4238x; 1.1644x over previous
//
#include <hip/hip_runtime.h>
#include <hip/hip_bf16.h>

// Problem: N=4,C=64,F=100,T=200,H=16 ; B=N*F=400, BT=80000
// r14: MFMA k_attn. r13 (489.9us) left k_attn ~115us of scalar VALU doing a
// 200x200x16 GEMM pair. New k_attn: per block (br,b), 4 waves own 16-row
// t-strips (m = w, w+4, ...). Per strip: Q A-frag direct from global
// (x0.25 folded, bf16); per 32-col chunk jj: 2x mfma_16x16x32_bf16 QK^T
// (B-frags from LDS bf16 K, k_xg-verified layout), fused mask
// (s>t -> P=1 == exp(0); s>199 -> P=0; replaces suffix-V trick exactly),
// 8 exp/lane, P->bf16 via per-wave 16x32 LDS chunk (in-wave transpose),
// 1x PV MFMA (B = V transposed in LDS) accumulating over jj. Row-sums S in
// fp32 via 16-lane shfl_xor; divide at store. LDS strides odd x 16B
// (80/464B) for low-conflict b128; ~30.5KB -> ~5 blocks/CU.
// k_lstm = r7 exact (197us, converged). k_ln1/k_out/k_prep unchanged.
// ws: header 204800 B (bihh fp32 @0, Wih-bf16 @8192), then per chunk:
//   xr bf16 [NB][200][64], xi same, h f32 [24][NB][200][16],
//   att f32 [8][NB][200][16].  Total = 204800 + NB*460800.

typedef __attribute__((ext_vector_type(8))) short bf16x8;
typedef __attribute__((ext_vector_type(4))) float f32x4;
typedef __attribute__((ext_vector_type(2))) float f32x2;

static __device__ __forceinline__ float bf2f(unsigned short u) {
  return __uint_as_float(((unsigned)u) << 16);
}
static __device__ __forceinline__ unsigned short f2bfu(float x) {
  __hip_bfloat16 h = __float2bfloat16(x);
  return *(unsigned short*)&h;
}
static __device__ __forceinline__ float sigf(float x) {
  return __fdividef(1.f, 1.f + __expf(-x));
}
static __device__ __forceinline__ float tanh_(float x) {
  return 1.f - __fdividef(2.f, __expf(2.f * x) + 1.f);  // safe at +-inf
}
static __device__ __forceinline__ f32x2 hh2(float v) {
  f32x2 r; r.x = v; r.y = v; return r;
}

// Broadcast lane (row-base + I) of h to all 16 lanes of its row.
// ROW_NEWBCAST:I = dpp_ctrl 0x150+I (CDNA2+/gfx950). Bit-exact equal to
// __shfl(h, (lane&48)+I, 64) since chains occupy aligned 16-lane rows.
template <int CTRL>
static __device__ __forceinline__ float dpp_bcast(float x) {
  int xi = __float_as_int(x);
  int r = __builtin_amdgcn_update_dpp(xi, xi, CTRL, 0xF, 0xF, false);
  return __int_as_float(r);
}

// ---------------- kernel A: LN1 over C -> xr/xi bf16 [bl][t][c]
__global__ __launch_bounds__(256) void k_ln1(const float* __restrict__ in,
    const float* __restrict__ w, const float* __restrict__ bsh,
    unsigned short* __restrict__ xr, unsigned short* __restrict__ xi, int b0) {
  __shared__ float is[64][101];   // [c][(tloc,ri)]
  __shared__ float os[100][65];   // [(tloc,ri)][c]
  int bid = blockIdx.x;
  int nfl = bid >> 2, tile = bid & 3;         // NB nf-local x 4 tiles of 50 t
  int nf = b0 + nfl;
  int t0 = tile * 50;
  int n = nf / 100, f = nf - n * 100;
  int tid = threadIdx.x;
  for (int i = 0; i < 7; ++i) {               // 64 rows x 25 float4
    int idx = tid + i * 256;
    if (idx < 1600) {
      int c = idx / 25, q = idx - c * 25;
      float4 v = *(const float4*)(in + (size_t)((n * 64 + c) * 100 + f) * 400
                                  + t0 * 2 + q * 4);
      is[c][q*4+0] = v.x; is[c][q*4+1] = v.y; is[c][q*4+2] = v.z; is[c][q*4+3] = v.w;
    }
  }
  __syncthreads();
  if (tid < 100) {
    float s = 0.f, ss = 0.f;
    #pragma unroll
    for (int c = 0; c < 64; ++c) { float v = is[c][tid]; s += v; ss += v * v; }
    float mean = s * 0.015625f;
    float var  = ss * 0.015625f - mean * mean;
    float rstd = rsqrtf(var + 1e-5f);
    #pragma unroll
    for (int c = 0; c < 64; ++c)
      os[tid][c] = (is[c][tid] - mean) * rstd * w[c] + bsh[c];
  }
  __syncthreads();
  for (int ri = 0; ri < 2; ++ri) {
    unsigned short* dst = ri ? xi : xr;
    for (int i = 0; i < 4; ++i) {             // 50 rows x 16 ushort4 per ri
      int idx = tid + i * 256;
      if (idx < 800) {
        int t = idx >> 4, q = idx & 15;
        ushort4 v;
        v.x = f2bfu(os[t*2+ri][q*4+0]); v.y = f2bfu(os[t*2+ri][q*4+1]);
        v.z = f2bfu(os[t*2+ri][q*4+2]); v.w = f2bfu(os[t*2+ri][q*4+3]);
        *(ushort4*)(dst + ((size_t)nfl * 200 + t0 + t) * 64 + q * 4) = v;
      }
    }
  }
}

// ---------------- prep: bihh = bih + bhh ; wbf = bf16(Wih)
__global__ void k_prep(const float* __restrict__ bih, const float* __restrict__ bhh,
                       const float* __restrict__ Wih, float* __restrict__ bihh,
                       unsigned short* __restrict__ wbf) {
  int i = blockIdx.x * 256 + threadIdx.x;
  if (i < 1536) bihh[i] = bih[i] + bhh[i];
  if (i < 98304) wbf[i] = f2bfu(Wih[i]);
}

// ---------------- kernel R: fused input-GEMM + LSTM recurrence (r7 exact).
// 1 wave = 4 chains of the SAME l (grid 24 x ceil(NB/4); dup chains clamp to
// b=NB-1, identical writes). lane = (q=lane>>4 chain, c=lane&15 unit).
// Every 4 steps, MGROUP computes pre-acts via 8 MFMAs:
//   A rows m = b_local*4+dt of x_sel (bf16), B = Wih[l] rows jt*16+c,
//   C = bias splat. D mapping (col=lane&15=unit c, row=q*4+r -> chain q,
//   dt=r) lands each value in its consumer lane. One group pipelined ahead.
// Whh[l] staged in LDS f32x2 wl[2][16][17] (conflict-free broadcast).
// h-broadcast via DPP row_newbcast.
__global__ __launch_bounds__(64) void k_lstm(const unsigned short* __restrict__ xr,
    const unsigned short* __restrict__ xi, const unsigned short* __restrict__ wbf,
    const float* __restrict__ bihh, const float* __restrict__ Whh,
    float* __restrict__ hbuf, int NB, int nbq) {
  __shared__ f32x2 wl[2][16][17];
  int lane = threadIdx.x;
  int q = lane >> 4, c = lane & 15;       // chain-in-block, unit
  int lq = blockIdx.x / nbq, q4 = blockIdx.x - lq * nbq;
  int l = lq;
  int b = q4 * 4 + q; if (b >= NB) b = NB - 1;   // dup chains: identical writes
  const float* Wg = Whh + (size_t)l * 1024;
  for (int idx = lane; idx < 1024; idx += 64) {  // coalesced one-time fill
    int row = idx >> 4, col = idx & 15;
    int gate = row >> 4, kk = row & 15;
    ((float*)&wl[gate >> 1][kk][col])[gate & 1] = Wg[idx];
  }
  __syncthreads();
  const f32x2* wla = wl[0][c];
  const f32x2* wlb = wl[1][c];
  int sel = (0xE54770 >> l) & 1;                 // per-lstm real/imag selection
  const unsigned short* xs = sel ? xi : xr;
  // A-frag source: lane (q,c) holds x row m = c -> b_local=c>>2, dt=c&3.
  int ba = q4 * 4 + (c >> 2); if (ba >= NB) ba = NB - 1;
  const unsigned short* ap2 = xs + ((size_t)ba * 200 + (c & 3)) * 64 + q * 8;
  // B-frag source: Wih row jt*16 + c, channels q*8+e (jt stride 1024 ushorts)
  const unsigned short* wrow = wbf + l * 4096 + c * 64 + q * 8;
  // bias splats (C-operand of first MFMA of each gate)
  float bv0 = bihh[l * 64 + c], bv1 = bihh[l * 64 + 16 + c];
  float bv2 = bihh[l * 64 + 32 + c], bv3 = bihh[l * 64 + 48 + c];
  f32x4 zb0 = {bv0, bv0, bv0, bv0}, zb1 = {bv1, bv1, bv1, bv1};
  f32x4 zb2 = {bv2, bv2, bv2, bv2}, zb3 = {bv3, bv3, bv3, bv3};
  float* hp = hbuf + ((size_t)l * NB + b) * 3200 + c;
  float h = 0.f, cs = 0.f;
  int tcur = 0;
#define MG1(DST, OFS, ZB, A0v, A1v) { \
  bf16x8 w0_ = *(const bf16x8*)(wrow + OFS); \
  bf16x8 w1_ = *(const bf16x8*)(wrow + OFS + 32); \
  f32x4 t_ = __builtin_amdgcn_mfma_f32_16x16x32_bf16(A0v, w0_, ZB, 0, 0, 0); \
  DST = __builtin_amdgcn_mfma_f32_16x16x32_bf16(A1v, w1_, t_, 0, 0, 0); }
#define MGROUP(D0, D1, D2, D3, A0v, A1v) \
  MG1(D0, 0, zb0, A0v, A1v) MG1(D1, 1024, zb1, A0v, A1v) \
  MG1(D2, 2048, zb2, A0v, A1v) MG1(D3, 3072, zb3, A0v, A1v)
#define HV(i) dpp_bcast<0x150 + i>(h)
#define LSTEP2(AC0, AC1, AC2, AC3, FLD) { \
  float hv0  = HV(0),  hv1  = HV(1),  hv2  = HV(2),  hv3  = HV(3);  \
  float hv4  = HV(4),  hv5  = HV(5),  hv6  = HV(6),  hv7  = HV(7);  \
  float hv8  = HV(8),  hv9  = HV(9),  hv10 = HV(10), hv11 = HV(11); \
  float hv12 = HV(12), hv13 = HV(13), hv14 = HV(14), hv15 = HV(15); \
  f32x2 pA = {AC0.FLD, AC1.FLD}; \
  f32x2 qA = {AC2.FLD, AC3.FLD}; \
  f32x2 pB = {0.f, 0.f}, qB = {0.f, 0.f}; \
  pA += wla[0]  * hh2(hv0);  pB += wla[1]  * hh2(hv1);  \
  qA += wlb[0]  * hh2(hv0);  qB += wlb[1]  * hh2(hv1);  \
  pA += wla[2]  * hh2(hv2);  pB += wla[3]  * hh2(hv3);  \
  qA += wlb[2]  * hh2(hv2);  qB += wlb[3]  * hh2(hv3);  \
  pA += wla[4]  * hh2(hv4);  pB += wla[5]  * hh2(hv5);  \
  qA += wlb[4]  * hh2(hv4);  qB += wlb[5]  * hh2(hv5);  \
  pA += wla[6]  * hh2(hv6);  pB += wla[7]  * hh2(hv7);  \
  qA += wlb[6]  * hh2(hv6);  qB += wlb[7]  * hh2(hv7);  \
  pA += wla[8]  * hh2(hv8);  pB += wla[9]  * hh2(hv9);  \
  qA += wlb[8]  * hh2(hv8);  qB += wlb[9]  * hh2(hv9);  \
  pA += wla[10] * hh2(hv10); pB += wla[11] * hh2(hv11); \
  qA += wlb[10] * hh2(hv10); qB += wlb[11] * hh2(hv11); \
  pA += wla[12] * hh2(hv12); pB += wla[13] * hh2(hv13); \
  qA += wlb[12] * hh2(hv12); qB += wlb[13] * hh2(hv13); \
  pA += wla[14] * hh2(hv14); pB += wla[15] * hh2(hv15); \
  qA += wlb[14] * hh2(hv14); qB += wlb[15] * hh2(hv15); \
  f32x2 p01 = pA + pB, p23 = qA + qB; \
  float ig_ = sigf(p01.x), fg_ = sigf(p01.y); \
  float gg_ = tanh_(p23.x), og_ = sigf(p23.y); \
  cs = fg_ * cs + ig_ * gg_; \
  h = og_ * tanh_(cs); \
  hp[tcur * 16] = h; ++tcur; }
  // prologue: group 0 pre-acts; prefetch A of group 1
  bf16x8 a0 = *(const bf16x8*)(ap2), a1 = *(const bf16x8*)(ap2 + 32);
  f32x4 c0, c1, c2, c3, n0, n1, n2, n3;
  MGROUP(c0, c1, c2, c3, a0, a1);
  ap2 += 256;
  a0 = *(const bf16x8*)(ap2); a1 = *(const bf16x8*)(ap2 + 32);
  for (int g = 0; g < 50; ++g) {
    LSTEP2(c0, c1, c2, c3, x)
    LSTEP2(c0, c1, c2, c3, y)
    MGROUP(n0, n1, n2, n3, a0, a1);      // pre-acts for group g+1
    if (g < 48) ap2 += 256;              // A of group g+2 (clamped at end)
    a0 = *(const bf16x8*)(ap2); a1 = *(const bf16x8*)(ap2 + 32);
    LSTEP2(c0, c1, c2, c3, z)
    LSTEP2(c0, c1, c2, c3, w)
    c0 = n0; c1 = n1; c2 = n2; c3 = n3;
  }
#undef LSTEP2
#undef HV
#undef MGROUP
#undef MG1
}

// ---------------- kernel C: MFMA attention per (branch, b). 4 waves; wave w
// owns t-strips m = w, w+4, ... (13 strips of 16 rows). softmax(energy*mask):
// masked (s>t) entries get weight exp(0)=1; s>199 padding gets 0.
// Per strip: A-frag = Q rows (x0.25, bf16) direct from global. Per 32-col
// chunk jj (7 chunks cover s 0..223): 2x mfma_16x16x32_bf16 QK^T with
// B-frags from Kb (bf16 K staged in LDS, rows 200..223 zero); mask+exp in
// fp32 (S accumulated); P->bf16 into per-wave Pc[16][32] chunk (in-wave LDS
// transpose); 1x PV MFMA with B-frags from Vt (V^T bf16). S reduced over the
// 16 lanes of each quad-group via shfl_xor; att = pv/S.
// LDS row strides are odd multiples of 16B (80B, 464B) -> <=2-way conflicts.
__global__ __launch_bounds__(256) void k_attn(const float* __restrict__ hbuf,
                                              float* __restrict__ att, int NB) {
  __shared__ unsigned short Kb[224][40];   // [s][k] bf16, 80B stride
  __shared__ unsigned short Vt[16][232];   // [k][s] bf16, 464B stride
  __shared__ unsigned short Pc[4][16][40]; // per-wave P chunk [t_loc][s_loc]
  int bid = blockIdx.x;                    // 8 br x NB
  int br = bid / NB, b = bid - br * NB;
  int tid = threadIdx.x;
  const float* qg = hbuf + ((size_t)(br * 3 + 0) * NB + b) * 3200;
  const float* kg = hbuf + ((size_t)(br * 3 + 1) * NB + b) * 3200;
  const float* vg = hbuf + ((size_t)(br * 3 + 2) * NB + b) * 3200;
  // zero Kb (incl. k-cols 16..39 and rows 200..223) and Vt (incl. s>=200)
  {
    unsigned* kz = (unsigned*)&Kb[0][0];       // 224*40/2 = 4480 u32
    for (int i = tid; i < 4480; i += 256) kz[i] = 0;
    unsigned* vz = (unsigned*)&Vt[0][0];       // 16*232/2 = 1856 u32
    for (int i = tid; i < 1856; i += 256) vz[i] = 0;
  }
  __syncthreads();
  for (int i = 0; i < 4; ++i) {            // 200 rows x 4 float4 of K and V
    int idx = tid + i * 256;
    if (idx < 800) {
      int s = idx >> 2, qq = idx & 3;
      float4 kv = *(const float4*)(kg + s * 16 + qq * 4);
      ushort4 kp;
      kp.x = f2bfu(kv.x); kp.y = f2bfu(kv.y);
      kp.z = f2bfu(kv.z); kp.w = f2bfu(kv.w);
      *(ushort4*)&Kb[s][qq * 4] = kp;      // 80B row stride -> 8B aligned
      float4 vv = *(const float4*)(vg + s * 16 + qq * 4);
      Vt[qq * 4 + 0][s] = f2bfu(vv.x);
      Vt[qq * 4 + 1][s] = f2bfu(vv.y);
      Vt[qq * 4 + 2][s] = f2bfu(vv.z);
      Vt[qq * 4 + 3][s] = f2bfu(vv.w);
    }
  }
  __syncthreads();
  int w = tid >> 6, lane = tid & 63;
  int q = lane >> 4, n = lane & 15;
  size_t obase = (size_t)(br * NB + b) * 200;
  for (int m = w; m <= 12; m += 4) {
    // A-frag: Q row 16m+n, k = q*8+e (k>=16 -> 0), x0.25 folded, bf16.
    bf16x8 aQ;
    {
      int trow = 16 * m + n;               // rows 200..207 read into kg region
      const float* qp = qg + trow * 16 + q * 8;   // (valid memory, unused rows)
      #pragma unroll
      for (int e = 0; e < 8; ++e) {
        float v = (q < 2) ? qp[e] * 0.25f : 0.f;
        aQ[e] = (short)f2bfu(v);
      }
    }
    f32x4 pv = {0.f, 0.f, 0.f, 0.f};
    float s40 = 0.f, s41 = 0.f, s42 = 0.f, s43 = 0.f;
    #pragma unroll 1
    for (int jj = 0; jj < 7; ++jj) {
      int sb = jj * 32;
      bf16x8 bK0 = *(const bf16x8*)&Kb[sb + n][q * 8];
      bf16x8 bK1 = *(const bf16x8*)&Kb[sb + 16 + n][q * 8];
      f32x4 z = {0.f, 0.f, 0.f, 0.f};
      f32x4 d0 = __builtin_amdgcn_mfma_f32_16x16x32_bf16(aQ, bK0, z, 0, 0, 0);
      f32x4 d1 = __builtin_amdgcn_mfma_f32_16x16x32_bf16(aQ, bK1, z, 0, 0, 0);
      int s0 = sb + n, s1 = sb + 16 + n;
      int tb = 16 * m + 4 * q;
      #pragma unroll
      for (int r = 0; r < 4; ++r) {
        int t = tb + r;
        float p0 = (s0 > 199) ? 0.f : ((s0 > t) ? 1.f : __expf(d0[r]));
        float p1 = (s1 > 199) ? 0.f : ((s1 > t) ? 1.f : __expf(d1[r]));
        if (r == 0) { s40 += p0 + p1; } else if (r == 1) { s41 += p0 + p1; }
        else if (r == 2) { s42 += p0 + p1; } else { s43 += p0 + p1; }
        Pc[w][4 * q + r][n]      = f2bfu(p0);
        Pc[w][4 * q + r][16 + n] = f2bfu(p1);
      }
      bf16x8 aP = *(const bf16x8*)&Pc[w][n][q * 8];
      bf16x8 bV = *(const bf16x8*)&Vt[n][sb + q * 8];
      pv = __builtin_amdgcn_mfma_f32_16x16x32_bf16(aP, bV, pv, 0, 0, 0);
    }
    // reduce S over the 16 lanes of this quad-group (masks 1,2,4,8)
    #pragma unroll
    for (int mm = 1; mm < 16; mm <<= 1) {
      s40 += __shfl_xor(s40, mm, 64);
      s41 += __shfl_xor(s41, mm, 64);
      s42 += __shfl_xor(s42, mm, 64);
      s43 += __shfl_xor(s43, mm, 64);
    }
    int tb = 16 * m + 4 * q;
    if (tb + 0 < 200) att[(obase + tb + 0) * 16 + n] = pv[0] * __fdividef(1.f, s40);
    if (tb + 1 < 200) att[(obase + tb + 1) * 16 + n] = pv[1] * __fdividef(1.f, s41);
    if (tb + 2 < 200) att[(obase + tb + 2) * 16 + n] = pv[2] * __fdividef(1.f, s42);
    if (tb + 3 < 200) att[(obase + tb + 3) * 16 + n] = pv[3] * __fdividef(1.f, s43);
  }
}

// ---------------- kernel D: combine branches + LN2 + complex linear + LN3 +
// PReLU + residual, with LDS transpose for coalesced [N,C,F,T,2] IO.
__global__ __launch_bounds__(256) void k_out(const float* __restrict__ att,
    const float* __restrict__ in,
    const float* __restrict__ ln2w, const float* __restrict__ ln2b,
    const float* __restrict__ lrw, const float* __restrict__ lrb,
    const float* __restrict__ liw, const float* __restrict__ lib,
    const float* __restrict__ ln3w, const float* __restrict__ ln3b,
    const float* __restrict__ pa, float* __restrict__ out, int b0, int NB) {
  __shared__ float as_[8][40][17];
  __shared__ float ys[40][2][17];
  __shared__ float zs[64][81];
  int bid = blockIdx.x;                 // NB nf-local x 5 tiles of 40 t
  int nfl = bid / 5, tile = bid - nfl * 5;
  int nf = b0 + nfl;
  int t0 = tile * 40;
  int n = nf / 100, f = nf - n * 100;
  int tid = threadIdx.x;
  for (int i = 0; i < 5; ++i) {         // att: 8 br x 40 t x 4 f4
    int idx = tid + i * 256;
    int br = idx / 160, r = idx - br * 160;
    int t = r >> 2, q = r & 3;
    float4 v = *(const float4*)(att + (((size_t)br * NB + nfl) * 200 + t0 + t) * 16 + q * 4);
    as_[br][t][q*4+0] = v.x; as_[br][t][q*4+1] = v.y;
    as_[br][t][q*4+2] = v.z; as_[br][t][q*4+3] = v.w;
  }
  __syncthreads();
  if (tid < 80) {                       // combine + LN2 per (t,ri)
    int t = tid >> 1, ri = tid & 1;
    float vv[16]; float s = 0.f, ss = 0.f;
    #pragma unroll
    for (int k = 0; k < 16; ++k) {
      float v;
      if (ri == 0) v = as_[0][t][k] - as_[1][t][k] - as_[2][t][k] - as_[3][t][k];
      else         v = as_[4][t][k] + as_[5][t][k] + as_[6][t][k] - as_[7][t][k];
      vv[k] = v; s += v; ss += v * v;
    }
    float mean = s * 0.0625f;
    float var  = ss * 0.0625f - mean * mean;
    float rstd = rsqrtf(var + 1e-5f);
    #pragma unroll
    for (int k = 0; k < 16; ++k)
      ys[t][ri][k] = (vv[k] - mean) * rstd * ln2w[k] + ln2b[k];
  }
  __syncthreads();
  // complex linear 16->64 + LN3 over c (wave = 64 lanes = c) + PReLU
  int wv = tid >> 6, cc = tid & 63;
  float lr[16], li[16];
  #pragma unroll
  for (int q = 0; q < 4; ++q) {
    float4 v = *(const float4*)(lrw + cc * 16 + q * 4);
    lr[q*4+0] = v.x; lr[q*4+1] = v.y; lr[q*4+2] = v.z; lr[q*4+3] = v.w;
    float4 u = *(const float4*)(liw + cc * 16 + q * 4);
    li[q*4+0] = u.x; li[q*4+1] = u.y; li[q*4+2] = u.z; li[q*4+3] = u.w;
  }
  float brc = lrb[cc], bic = lib[cc];
  float w3 = ln3w[cc], b3 = ln3b[cc];
  float aP = pa[0];
  for (int tt = wv; tt < 40; tt += 4) {
    float zr = brc - bic, zi = brc + bic;
    #pragma unroll
    for (int k = 0; k < 16; ++k) {
      float yr = ys[tt][0][k], yi = ys[tt][1][k];
      zr += yr * lr[k] - yi * li[k];
      zi += yi * lr[k] + yr * li[k];
    }
    float s1 = zr, s2 = zr * zr, s3 = zi, s4 = zi * zi;
    #pragma unroll
    for (int m = 1; m < 64; m <<= 1) {
      s1 += __shfl_xor(s1, m, 64);
      s2 += __shfl_xor(s2, m, 64);
      s3 += __shfl_xor(s3, m, 64);
      s4 += __shfl_xor(s4, m, 64);
    }
    float mr = s1 * 0.015625f, vr = s2 * 0.015625f - mr * mr;
    float mi = s3 * 0.015625f, vi = s4 * 0.015625f - mi * mi;
    float r1 = (zr - mr) * rsqrtf(vr + 1e-5f) * w3 + b3;
    float r2 = (zi - mi) * rsqrtf(vi + 1e-5f) * w3 + b3;
    r1 = r1 >= 0.f ? r1 : aP * r1;
    r2 = r2 >= 0.f ? r2 : aP * r2;
    zs[cc][tt * 2 + 0] = r1;
    zs[cc][tt * 2 + 1] = r2;
  }
  __syncthreads();
  for (int i = 0; i < 5; ++i) {         // residual + coalesced write
    int idx = tid + i * 256;            // 64 c x 20 f4
    int c = idx / 20, q = idx - c * 20;
    size_t gaddr = (size_t)((n * 64 + c) * 100 + f) * 400 + t0 * 2 + q * 4;
    float4 v = *(const float4*)(in + gaddr);
    float4 z;
    z.x = zs[c][q*4+0] + v.x; z.y = zs[c][q*4+1] + v.y;
    z.z = zs[c][q*4+2] + v.z; z.w = zs[c][q*4+3] + v.w;
    *(float4*)(out + gaddr) = z;
  }
}

extern "C" void kernel_launch(void* const* d_in, const int* in_sizes, int n_in,
                              void* d_out, int out_size, void* d_ws, size_t ws_size,
                              hipStream_t stream) {
  (void)in_sizes; (void)n_in; (void)out_size;
  const float* inputs = (const float*)d_in[0];
  const float* Wih  = (const float*)d_in[1];
  const float* Whh  = (const float*)d_in[2];
  const float* bih  = (const float*)d_in[3];
  const float* bhh  = (const float*)d_in[4];
  const float* ln1w = (const float*)d_in[5];
  const float* ln1b = (const float*)d_in[6];
  const float* ln2w = (const float*)d_in[7];
  const float* ln2b = (const float*)d_in[8];
  const float* lrw  = (const float*)d_in[9];
  const float* lrb  = (const float*)d_in[10];
  const float* liw  = (const float*)d_in[11];
  const float* lib  = (const float*)d_in[12];
  const float* ln3w = (const float*)d_in[13];
  const float* ln3b = (const float*)d_in[14];
  const float* pa   = (const float*)d_in[15];
  float* out = (float*)d_out;
  char* ws = (char*)d_ws;

  // pick largest chunk NB (400,200,100,50,25) whose buffers fit ws_size
  // per-b: xr+xi 51200 + h 307200 + att 102400 = 460800 B
  int NB = 400;
  while (NB > 25 && 204800ull + (size_t)NB * 460800ull > ws_size) NB /= 2;
  int nch = 400 / NB;

  float* bihh = (float*)(ws + 0);                        // 6 KB
  unsigned short* wbf = (unsigned short*)(ws + 8192);    // 192 KB bf16 Wih
  size_t o_xr = 204800;
  size_t o_xi = o_xr + (size_t)NB * 25600;
  size_t o_h  = o_xi + (size_t)NB * 25600;
  size_t o_at = o_h  + (size_t)NB * 307200;
  unsigned short* xr = (unsigned short*)(ws + o_xr);
  unsigned short* xi = (unsigned short*)(ws + o_xi);
  float* hbuf = (float*)(ws + o_h);
  float* att  = (float*)(ws + o_at);

  k_prep<<<384, 256, 0, stream>>>(bih, bhh, Wih, bihh, wbf);
  int nbq = (NB + 3) >> 2;              // 4-chain groups per l
  for (int ch = 0; ch < nch; ++ch) {
    int b0 = ch * NB;
    k_ln1 <<<NB * 4,   256, 0, stream>>>(inputs, ln1w, ln1b, xr, xi, b0);
    k_lstm<<<24 * nbq,  64, 0, stream>>>(xr, xi, wbf, bihh, Whh, hbuf, NB, nbq);
    k_attn<<<8 * NB,   256, 0, stream>>>(hbuf, att, NB);
    k_out <<<NB * 5,   256, 0, stream>>>(att, inputs, ln2w, ln2b, lrw, lrb,
                                         liw, lib, ln3w, ln3b, pa, out, b0, NB);
  }
}